// Round 1
// baseline (148.615 us; speedup 1.0000x reference)
//
#include <hip/hip_runtime.h>
#include <math.h>

// DotProductAttention: B=16, Q=2048, K=2048, D=128, fp32 in/out.
// Query-axis masking only: rows q >= valid_lens[b] -> uniform softmax -> mean(V).
//
// R10: SINGLE-PASS FLASH. Reference has NO key-axis mask -> every active q-row
// needs all 2048 keys; K+V per batch is just 1 MB f16 = 32 slices of 32 KB.
// Each block owns one (b, 128-q tile), loops all 32 key-slices with a
// double-buffered 64 KB LDS ping-pong (T3 minimum-2-phase: issue next-slice
// global_load_lds BEFORE computing current, single barrier per slice).
// This deletes Po (16 f16 planes, ~70 MB w + ~67 MB r), Lb, the combine
// kernel, and 15/16 of the Qh re-reads. O accumulates fp32 across all keys
// (better accuracy than f16 partials). Fully-masked tiles/waves write
// mean(V) from fp32 column sums (exact path, as combine did).
// Grid (x=b, y=qt): linear%8 = b%8 -> all 16 q-tiles of a batch share one
// XCD's L2 (1 MB K/V slice resident; 32 blocks/XCD = exactly fills).
// All MFMA fragment/slot/swizzle formulas verbatim from R5/R8-verified code:
// 32x32x16, S^T slot-permutation pi = swap bits 2<->3, VT=64 Vt swizzle.
//
// ws: sumV 8K | Kh 8.39M | Vt 8.39M | Qh 8.39M  (~25.2 MB total).

#define Bn 16
#define Qn 2048
#define Kn 2048
#define Dn 128
#define SCALE 0.08838834764831845f  // 1/sqrt(128)

typedef _Float16 f16;
typedef _Float16 f16x8_t __attribute__((ext_vector_type(8)));
typedef float f32x16_t __attribute__((ext_vector_type(16)));

typedef __attribute__((address_space(1))) const unsigned int glb_u32;
typedef __attribute__((address_space(3))) unsigned int lds_u32;

__device__ __forceinline__ void g2l16(const void* g, void* l) {
  __builtin_amdgcn_global_load_lds((glb_u32*)g, (lds_u32*)l, 16, 0, 0);
}

// ---------------- prep: K->f16 swizzled rows, V->Vt 64-key tiles, Q->f16,
// colsum. grid (32, 4, 16) block (32,8).   [verbatim from R8/R9, VT=64 + Qh]
// Kh key-row k (256B): granule G=d>>3 at slot (G&8)|((G&7)^(k&7))  [verified]
// Vt tile [b][k/64][d][kk] 16KB, G=kk>>3 at G^(d&7)                [verified]
// Qh: plain row-major f16.

__global__ void __launch_bounds__(256) prep_kernel(
    const float* __restrict__ Qg, const float* __restrict__ Kg,
    const float* __restrict__ Vg, f16* __restrict__ Qh, f16* __restrict__ Kh,
    f16* __restrict__ Vt, float* __restrict__ sv) {
  __shared__ float ps[8][32];
  const int b = blockIdx.z;
  const int x = threadIdx.x, y = threadIdx.y;

  // K and Q: 16 rows per block, one granule (8 d) per thread
  {
    const int lb = (b * 4 + blockIdx.y) * 32 + blockIdx.x;  // 0..2047
    const int t = y * 32 + x;
    const size_t key = (size_t)lb * 16 + (t >> 4);  // global (b*2048+k)
    const int G = t & 15;
    const float* kp = Kg + (key << 7) + G * 8;
    float4 f0 = *(const float4*)kp;
    float4 f1 = *(const float4*)(kp + 4);
    f16x8_t o;
    o[0] = (f16)f0.x; o[1] = (f16)f0.y; o[2] = (f16)f0.z; o[3] = (f16)f0.w;
    o[4] = (f16)f1.x; o[5] = (f16)f1.y; o[6] = (f16)f1.z; o[7] = (f16)f1.w;
    const int gs = (G & 8) | ((G & 7) ^ ((int)key & 7));
    *(f16x8_t*)(Kh + (key << 7) + (gs << 3)) = o;

    const float* qp = Qg + (key << 7) + G * 8;
    float4 q0 = *(const float4*)qp;
    float4 q1 = *(const float4*)(qp + 4);
    f16x8_t oq;
    oq[0] = (f16)q0.x; oq[1] = (f16)q0.y; oq[2] = (f16)q0.z; oq[3] = (f16)q0.w;
    oq[4] = (f16)q1.x; oq[5] = (f16)q1.y; oq[6] = (f16)q1.z; oq[7] = (f16)q1.w;
    *(f16x8_t*)(Qh + (key << 7) + G * 8) = oq;  // plain row-major
  }

  // V: 64 keys x 32 d per block; thread owns one Vt granule in-register
  const int k0 = blockIdx.x * 64, d0 = blockIdx.y * 32;
  const int d = d0 + x;
  const float* vp = Vg + ((size_t)b * Kn + k0 + y * 8) * Dn + d;
  float s = 0.f;
  f16x8_t gr;
#pragma unroll
  for (int j = 0; j < 8; j++) {
    float v = vp[(size_t)j * Dn];
    s += v;
    gr[j] = (f16)v;
  }
  {
    const int kb = k0 >> 6;
    const int G = y;  // kk granule 0..7
    const int gs = G ^ (d & 7);
    *(f16x8_t*)(Vt + (((size_t)(b * (Kn / 64) + kb) * 128 + d) << 6) + (gs << 3)) = gr;
  }

  // column sums for the masked fast path
  ps[y][x] = s;
  __syncthreads();
  if (y == 0) {
    float tot = 0.f;
#pragma unroll
    for (int j = 0; j < 8; j++) tot += ps[j][x];
    atomicAdd(&sv[b * Dn + d0 + x], tot);
  }
}

// valid_lens may be stored as int32 or int64. Sniff: odd words all zero -> 64.
__device__ __forceinline__ int load_vl(const int* __restrict__ vlp, int b) {
  bool is64 = true;
#pragma unroll
  for (int i = 1; i < 16; i += 2) is64 = is64 && (vlp[i] == 0);
  return is64 ? vlp[2 * b] : vlp[b];
}

// ---------------- flash_sp: single-pass. grid (Bn, 16) block 256.
// Block = (b, 128-q tile). Loops all 32 key-slices (64 keys each), LDS
// double-buffered 2x(16K+16K). One barrier per slice; next-slice DMA issued
// before compute so it overlaps (~1000 cyc compute covers ~300-600 cyc L2).

__global__ void __launch_bounds__(256, 2) flash_sp(
    const f16* __restrict__ Qh, const f16* __restrict__ Kh,
    const f16* __restrict__ Vt, const int* __restrict__ vlp,
    const float* __restrict__ sv, float* __restrict__ Out) {
  const int b = blockIdx.x;
  const int qt = blockIdx.y;
  const int q0 = qt << 7;
  const int vl = load_vl(vlp, b);
  const int tid = threadIdx.x;

  if (q0 >= vl) {
    // fully-masked tile: every row = mean(V), exact from fp32 column sums
    const float invK = 1.0f / (float)Kn;
    const int row = tid >> 1, h = tid & 1;  // 2 threads/row, 64 d each
    const float4* svp = (const float4*)(sv + b * Dn + h * 64);
    float4* op = (float4*)(Out + ((size_t)b * Qn + q0 + row) * Dn + h * 64);
#pragma unroll
    for (int i = 0; i < 16; i++) {
      float4 s4 = svp[i];
      op[i] = make_float4(s4.x * invK, s4.y * invK, s4.z * invK, s4.w * invK);
    }
    return;  // uniform per block: no barrier divergence
  }

  __shared__ __align__(16) f16 Ks[2][64 * 128];  // 2 x 16 KB
  __shared__ __align__(16) f16 Vs[2][128 * 64];  // 2 x 16 KB

  const int wave = tid >> 6, lane = tid & 63;
  const int H = lane >> 5, l5 = lane & 31;
  const int qbase = q0 + wave * 32;
  const bool wact = qbase < vl;  // fully-masked WAVE: skip compute, keep barriers
  const int q_lane = qbase + l5;
  const float sc = (q_lane >= vl) ? 0.f : SCALE;  // masked row: p=1 -> mean(V)

  // pi = swap bits 2<->3: A-row slot l5 holds physical key pi(l5) [verified]
  const int krow = (l5 & 0x13) | ((l5 & 4) << 1) | ((l5 & 8) >> 1);
  const int krow7 = krow & 7;

  // Q fragment (B-operand of S^T), loaded ONCE per block
  f16x8_t qf[8];
  if (wact) {
    const f16* qp = Qh + ((size_t)b * Qn + q_lane) * Dn + 8 * H;
#pragma unroll
    for (int s = 0; s < 8; s++) qf[s] = *(const f16x8_t*)(qp + 16 * s);
  }

  f32x16_t O[4];
#pragma unroll
  for (int i = 0; i < 4; i++) O[i] = (f32x16_t)(0.f);
  float l_lane = 0.f;

  const char* KgT = (const char*)Kh + ((size_t)b * Kn << 8);
  const char* VgT = (const char*)Vt + ((size_t)(b * (Kn / 64)) << 14);

  // stage slice 0 into buf 0
  {
    const char* kg = KgT + wave * 4096 + lane * 16;
    const char* vg = VgT + wave * 4096 + lane * 16;
    f16* kl = Ks[0] + wave * 2048;
    f16* vli = Vs[0] + wave * 2048;
#pragma unroll
    for (int i = 0; i < 4; i++) {
      g2l16(kg + i * 1024, kl + i * 512);
      g2l16(vg + i * 1024, vli + i * 512);
    }
  }
  __syncthreads();

  int buf = 0;
  for (int sl = 0; sl < 32; sl++) {
    // issue next slice's DMA first -> overlaps with compute below
    if (sl < 31) {
      const char* kg = KgT + (size_t)(sl + 1) * 16384 + wave * 4096 + lane * 16;
      const char* vg = VgT + (size_t)(sl + 1) * 16384 + wave * 4096 + lane * 16;
      f16* kl = Ks[buf ^ 1] + wave * 2048;
      f16* vli = Vs[buf ^ 1] + wave * 2048;
#pragma unroll
      for (int i = 0; i < 4; i++) {
        g2l16(kg + i * 1024, kl + i * 512);
        g2l16(vg + i * 1024, vli + i * 512);
      }
    }

    if (wact) {
#pragma unroll
      for (int sub = 0; sub < 2; sub++) {
        // S^T = K.Q^T over keys sl*64 + sub*32 .. +31   [formulas verbatim]
        f32x16_t T = (f32x16_t)(0.f);
        const f16* krp = Ks[buf] + ((sub * 32 + krow) << 7);
#pragma unroll
        for (int s = 0; s < 8; s++) {
          const int G = 2 * s + H;
          const int gs = (G & 8) | ((G & 7) ^ krow7);
          f16x8_t kf = *(const f16x8_t*)(krp + (gs << 3));
          T = __builtin_amdgcn_mfma_f32_32x32x16_f16(kf, qf[s], T, 0, 0, 0);
        }

        // p = exp(s*sc); C-regs are the PV A-fragment
        f16x8_t pf0, pf1;
        float ls = 0.f;
#pragma unroll
        for (int r = 0; r < 8; r++) {
          float p = __expf(T[r] * sc);
          ls += p;
          pf0[r] = (f16)p;
        }
#pragma unroll
        for (int r = 8; r < 16; r++) {
          float p = __expf(T[r] * sc);
          ls += p;
          pf1[r - 8] = (f16)p;
        }
        l_lane += ls;

        // O += P.V : B-frags from swizzled Vs (VT=64 layout)  [verbatim]
#pragma unroll
        for (int dt = 0; dt < 4; dt++) {
          const f16* vrp = Vs[buf] + ((dt * 32 + l5) << 6);
          const int G0 = sub * 4 + H, G1 = sub * 4 + 2 + H;
          const int gs0 = G0 ^ (l5 & 7);
          const int gs1 = G1 ^ (l5 & 7);
          f16x8_t vf0 = *(const f16x8_t*)(vrp + (gs0 << 3));
          f16x8_t vf1 = *(const f16x8_t*)(vrp + (gs1 << 3));
          O[dt] = __builtin_amdgcn_mfma_f32_32x32x16_f16(pf0, vf0, O[dt], 0, 0, 0);
          O[dt] = __builtin_amdgcn_mfma_f32_32x32x16_f16(pf1, vf1, O[dt], 0, 0, 0);
        }
      }
    }
    __syncthreads();  // buf staged-next complete + safe to overwrite buf
    buf ^= 1;
  }

  // epilogue: normalize in-register, write fp32 Out directly (once)
  float* op = Out + ((size_t)b * Qn + qbase) * Dn;
  if (wact) {
    float ll = l_lane + __shfl_xor(l_lane, 32);  // lane l5 holds l(q=qbase+l5)
    float inv[16];
#pragma unroll
    for (int r = 0; r < 16; r++) {
      const int qrow = (r & 3) + 8 * (r >> 2) + 4 * H;  // PV C-layout row
      inv[r] = 1.0f / __shfl(ll, qrow);
    }
#pragma unroll
    for (int dt = 0; dt < 4; dt++) {
#pragma unroll
      for (int r = 0; r < 16; r++) {
        const int qrow = (r & 3) + 8 * (r >> 2) + 4 * H;
        op[(size_t)qrow * Dn + dt * 32 + l5] = O[dt][r] * inv[r];
      }
    }
  } else {
    // fully-masked wave inside an active block: exact mean(V)
    const float invK = 1.0f / (float)Kn;
#pragma unroll
    for (int dt = 0; dt < 4; dt++) {
      const float svv = sv[b * Dn + dt * 32 + l5] * invK;
#pragma unroll
      for (int r = 0; r < 16; r++) {
        const int qrow = (r & 3) + 8 * (r >> 2) + 4 * H;
        op[(size_t)qrow * Dn + dt * 32 + l5] = svv;
      }
    }
  }
}

// ---------------- launch ----------------

extern "C" void kernel_launch(void* const* d_in, const int* in_sizes, int n_in,
                              void* d_out, int out_size, void* d_ws, size_t ws_size,
                              hipStream_t stream) {
  const float* Qg = (const float*)d_in[0];
  const float* Kg = (const float*)d_in[1];
  const float* Vg = (const float*)d_in[2];
  const int* vl = (const int*)d_in[3];
  float* Out = (float*)d_out;

  char* ws = (char*)d_ws;
  const size_t kv = (size_t)Bn * Kn * Dn * 2;  // 8.39 MB each
  float* sumV = (float*)ws;                    // 8 KB
  f16* Kh = (f16*)(ws + 8192);
  f16* Vt = (f16*)(ws + 8192 + kv);
  f16* Qh = (f16*)(ws + 8192 + 2 * kv);
  // total need: 8 KB + 3 * 8.39 MB = ~25.2 MB (harness ws is 256 MiB)

  hipMemsetAsync(sumV, 0, Bn * Dn * sizeof(float), stream);

  prep_kernel<<<dim3(32, 4, Bn), dim3(32, 8), 0, stream>>>(
      Qg, Kg, Vg, Qh, Kh, Vt, sumV);
  // grid (x=b, y=qt): linear%8 = b%8 -> same-b blocks share an XCD L2
  flash_sp<<<dim3(Bn, 16), 256, 0, stream>>>(Qh, Kh, Vt, vl, sumV, Out);
}

// Round 2
// 141.907 us; speedup vs baseline: 1.0473x; 1.0473x over previous
//
#include <hip/hip_runtime.h>
#include <math.h>

// DotProductAttention: B=16, Q=2048, K=2048, D=128, fp32 in/out.
// Query-axis masking only: rows q >= valid_lens[b] -> uniform softmax -> mean(V).
//
// R11: SEG=4 PARALLELISM FIX. R10 (single-pass) proved traffic is solved
// (flash FETCH 10MB, all K/V L2-resident) but occupancy was 5.5%: only
// ~128 active blocks (masked tiles exit) -> 1 wave/SIMD on half the CUs,
// pure latency-bound, MfmaUtil 8.9%. Split K into 4 segments of 512 keys:
// ~512 active blocks x 4 waves = ~8 waves/CU (2 blocks/CU, 64KB LDS each),
// keeping R10's double-buffered prefetch-before-compute slice loop.
// f16 partial planes (4) + proven combine<4> close the softmax.
// Grid (b fastest) -> linear%8 = b%8 -> per-batch K/V stays XCD-local.
// All MFMA fragment/slot/swizzle formulas verbatim from R5/R8-verified code:
// 32x32x16, S^T slot-permutation pi = swap bits 2<->3, VT=64 Vt swizzle.
//
// ws: sumV 8K | Kh 8.39M | Vt 8.39M | Qh 8.39M | Po 4x8.39M | Lb 4x128K
//     (~59.3 MB total; falls back to single-pass R10 kernel if ws < that).

#define Bn 16
#define Qn 2048
#define Kn 2048
#define Dn 128
#define SCALE 0.08838834764831845f  // 1/sqrt(128)

typedef _Float16 f16;
typedef _Float16 f16x8_t __attribute__((ext_vector_type(8)));
typedef float f32x16_t __attribute__((ext_vector_type(16)));

typedef __attribute__((address_space(1))) const unsigned int glb_u32;
typedef __attribute__((address_space(3))) unsigned int lds_u32;

__device__ __forceinline__ void g2l16(const void* g, void* l) {
  __builtin_amdgcn_global_load_lds((glb_u32*)g, (lds_u32*)l, 16, 0, 0);
}

// ---------------- prep: K->f16 swizzled rows, V->Vt 64-key tiles, Q->f16,
// colsum. grid (32, 4, 16) block (32,8).   [verbatim, HW-verified]
// Kh key-row k (256B): granule G=d>>3 at slot (G&8)|((G&7)^(k&7))
// Vt tile [b][k/64][d][kk] 16KB, G=kk>>3 at G^(d&7)
// Qh: plain row-major f16.

__global__ void __launch_bounds__(256) prep_kernel(
    const float* __restrict__ Qg, const float* __restrict__ Kg,
    const float* __restrict__ Vg, f16* __restrict__ Qh, f16* __restrict__ Kh,
    f16* __restrict__ Vt, float* __restrict__ sv) {
  __shared__ float ps[8][32];
  const int b = blockIdx.z;
  const int x = threadIdx.x, y = threadIdx.y;

  // K and Q: 16 rows per block, one granule (8 d) per thread
  {
    const int lb = (b * 4 + blockIdx.y) * 32 + blockIdx.x;  // 0..2047
    const int t = y * 32 + x;
    const size_t key = (size_t)lb * 16 + (t >> 4);  // global (b*2048+k)
    const int G = t & 15;
    const float* kp = Kg + (key << 7) + G * 8;
    float4 f0 = *(const float4*)kp;
    float4 f1 = *(const float4*)(kp + 4);
    f16x8_t o;
    o[0] = (f16)f0.x; o[1] = (f16)f0.y; o[2] = (f16)f0.z; o[3] = (f16)f0.w;
    o[4] = (f16)f1.x; o[5] = (f16)f1.y; o[6] = (f16)f1.z; o[7] = (f16)f1.w;
    const int gs = (G & 8) | ((G & 7) ^ ((int)key & 7));
    *(f16x8_t*)(Kh + (key << 7) + (gs << 3)) = o;

    const float* qp = Qg + (key << 7) + G * 8;
    float4 q0 = *(const float4*)qp;
    float4 q1 = *(const float4*)(qp + 4);
    f16x8_t oq;
    oq[0] = (f16)q0.x; oq[1] = (f16)q0.y; oq[2] = (f16)q0.z; oq[3] = (f16)q0.w;
    oq[4] = (f16)q1.x; oq[5] = (f16)q1.y; oq[6] = (f16)q1.z; oq[7] = (f16)q1.w;
    *(f16x8_t*)(Qh + (key << 7) + G * 8) = oq;  // plain row-major
  }

  // V: 64 keys x 32 d per block; thread owns one Vt granule in-register
  const int k0 = blockIdx.x * 64, d0 = blockIdx.y * 32;
  const int d = d0 + x;
  const float* vp = Vg + ((size_t)b * Kn + k0 + y * 8) * Dn + d;
  float s = 0.f;
  f16x8_t gr;
#pragma unroll
  for (int j = 0; j < 8; j++) {
    float v = vp[(size_t)j * Dn];
    s += v;
    gr[j] = (f16)v;
  }
  {
    const int kb = k0 >> 6;
    const int G = y;  // kk granule 0..7
    const int gs = G ^ (d & 7);
    *(f16x8_t*)(Vt + (((size_t)(b * (Kn / 64) + kb) * 128 + d) << 6) + (gs << 3)) = gr;
  }

  // column sums for the masked fast path
  ps[y][x] = s;
  __syncthreads();
  if (y == 0) {
    float tot = 0.f;
#pragma unroll
    for (int j = 0; j < 8; j++) tot += ps[j][x];
    atomicAdd(&sv[b * Dn + d0 + x], tot);
  }
}

// valid_lens may be stored as int32 or int64. Sniff: odd words all zero -> 64.
__device__ __forceinline__ int load_vl(const int* __restrict__ vlp, int b) {
  bool is64 = true;
#pragma unroll
  for (int i = 1; i < 16; i += 2) is64 = is64 && (vlp[i] == 0);
  return is64 ? vlp[2 * b] : vlp[b];
}

// ---------------- flash4: SEG=4 partial flash. grid (Bn, 16, 4) block 256.
// Block = (b, 128-q tile, 512-key segment): 8 slices of 64 keys, LDS
// double-buffered 2x(16K+16K), prefetch-next-before-compute, 1 barrier/slice.
// Writes unnormalized f16 O-partials + l-partials; combine<4> finishes.

__global__ void __launch_bounds__(256, 2) flash4(
    const f16* __restrict__ Qh, const f16* __restrict__ Kh,
    const f16* __restrict__ Vt, const int* __restrict__ vlp,
    f16* __restrict__ Po, float* __restrict__ Lb) {
  const int b = blockIdx.x;
  const int qt = blockIdx.y;
  const int seg = blockIdx.z;
  const int q0 = qt << 7;
  const int vl = load_vl(vlp, b);
  if (q0 >= vl) return;  // fully-masked tile: combine writes mean(V)

  __shared__ __align__(16) f16 Ks[2][64 * 128];  // 2 x 16 KB
  __shared__ __align__(16) f16 Vs[2][128 * 64];  // 2 x 16 KB

  const int tid = threadIdx.x;
  const int wave = tid >> 6, lane = tid & 63;
  const int H = lane >> 5, l5 = lane & 31;
  const int qbase = q0 + wave * 32;
  const bool wact = qbase < vl;  // masked wave: stage+barrier only
  const int q_lane = qbase + l5;
  const float sc = (q_lane >= vl) ? 0.f : SCALE;  // masked row: p=1

  // pi = swap bits 2<->3: A-row slot l5 holds physical key pi(l5) [verified]
  const int krow = (l5 & 0x13) | ((l5 & 4) << 1) | ((l5 & 8) >> 1);
  const int krow7 = krow & 7;

  // Q fragment (B-operand of S^T), loaded once
  f16x8_t qf[8];
  if (wact) {
    const f16* qp = Qh + ((size_t)b * Qn + q_lane) * Dn + 8 * H;
#pragma unroll
    for (int s = 0; s < 8; s++) qf[s] = *(const f16x8_t*)(qp + 16 * s);
  }

  f32x16_t O[4];
#pragma unroll
  for (int i = 0; i < 4; i++) O[i] = (f32x16_t)(0.f);
  float l_lane = 0.f;

  // segment base: keys seg*512 .. +511
  const char* KgT = (const char*)Kh + (((size_t)b * Kn + seg * 512) << 8);
  const char* VgT = (const char*)Vt + ((size_t)(b * (Kn / 64) + seg * 8) << 14);

  // stage slice 0 into buf 0
  {
    const char* kg = KgT + wave * 4096 + lane * 16;
    const char* vg = VgT + wave * 4096 + lane * 16;
    f16* kl = Ks[0] + wave * 2048;
    f16* vli = Vs[0] + wave * 2048;
#pragma unroll
    for (int i = 0; i < 4; i++) {
      g2l16(kg + i * 1024, kl + i * 512);
      g2l16(vg + i * 1024, vli + i * 512);
    }
  }
  __syncthreads();

  int buf = 0;
  for (int sl = 0; sl < 8; sl++) {
    // issue next slice's DMA first -> overlaps with compute below
    if (sl < 7) {
      const char* kg = KgT + (size_t)(sl + 1) * 16384 + wave * 4096 + lane * 16;
      const char* vg = VgT + (size_t)(sl + 1) * 16384 + wave * 4096 + lane * 16;
      f16* kl = Ks[buf ^ 1] + wave * 2048;
      f16* vli = Vs[buf ^ 1] + wave * 2048;
#pragma unroll
      for (int i = 0; i < 4; i++) {
        g2l16(kg + i * 1024, kl + i * 512);
        g2l16(vg + i * 1024, vli + i * 512);
      }
    }

    if (wact) {
#pragma unroll
      for (int sub = 0; sub < 2; sub++) {
        // S^T = K.Q^T over keys (seg*512 + sl*64 + sub*32)..+31  [verbatim]
        f32x16_t T = (f32x16_t)(0.f);
        const f16* krp = Ks[buf] + ((sub * 32 + krow) << 7);
#pragma unroll
        for (int s = 0; s < 8; s++) {
          const int G = 2 * s + H;
          const int gs = (G & 8) | ((G & 7) ^ krow7);
          f16x8_t kf = *(const f16x8_t*)(krp + (gs << 3));
          T = __builtin_amdgcn_mfma_f32_32x32x16_f16(kf, qf[s], T, 0, 0, 0);
        }

        // p = exp(s*sc); C-regs are the PV A-fragment
        f16x8_t pf0, pf1;
        float ls = 0.f;
#pragma unroll
        for (int r = 0; r < 8; r++) {
          float p = __expf(T[r] * sc);
          ls += p;
          pf0[r] = (f16)p;
        }
#pragma unroll
        for (int r = 8; r < 16; r++) {
          float p = __expf(T[r] * sc);
          ls += p;
          pf1[r - 8] = (f16)p;
        }
        l_lane += ls;

        // O += P.V : B-frags from swizzled Vs (VT=64 layout)  [verbatim]
#pragma unroll
        for (int dt = 0; dt < 4; dt++) {
          const f16* vrp = Vs[buf] + ((dt * 32 + l5) << 6);
          const int G0 = sub * 4 + H, G1 = sub * 4 + 2 + H;
          const int gs0 = G0 ^ (l5 & 7);
          const int gs1 = G1 ^ (l5 & 7);
          f16x8_t vf0 = *(const f16x8_t*)(vrp + (gs0 << 3));
          f16x8_t vf1 = *(const f16x8_t*)(vrp + (gs1 << 3));
          O[dt] = __builtin_amdgcn_mfma_f32_32x32x16_f16(pf0, vf0, O[dt], 0, 0, 0);
          O[dt] = __builtin_amdgcn_mfma_f32_32x32x16_f16(pf1, vf1, O[dt], 0, 0, 0);
        }
      }
    }
    __syncthreads();  // next-slice DMA complete + buf safe to overwrite
    buf ^= 1;
  }

  if (!wact) return;

  // epilogue: unnormalized partials  [verbatim from R0 flash_q]
  float ll = l_lane + __shfl_xor(l_lane, 32);
  if (lane < 32) Lb[(size_t)(seg * Bn + b) * Qn + qbase + l5] = ll;

  f16* po = Po + ((size_t)(seg * Bn + b) * Qn + qbase) * Dn;
#pragma unroll
  for (int dt = 0; dt < 4; dt++) {
#pragma unroll
    for (int r = 0; r < 16; r++) {
      const int qrow = (r & 3) + 8 * (r >> 2) + 4 * H;  // PV C-layout row
      po[(size_t)qrow * Dn + dt * 32 + l5] = (f16)O[dt][r];
    }
  }
}

// ---------------- flash_sp: single-pass fallback (R10, proven passing) ----

__global__ void __launch_bounds__(256, 2) flash_sp(
    const f16* __restrict__ Qh, const f16* __restrict__ Kh,
    const f16* __restrict__ Vt, const int* __restrict__ vlp,
    const float* __restrict__ sv, float* __restrict__ Out) {
  const int b = blockIdx.x;
  const int qt = blockIdx.y;
  const int q0 = qt << 7;
  const int vl = load_vl(vlp, b);
  const int tid = threadIdx.x;

  if (q0 >= vl) {
    const float invK = 1.0f / (float)Kn;
    const int row = tid >> 1, h = tid & 1;
    const float4* svp = (const float4*)(sv + b * Dn + h * 64);
    float4* op = (float4*)(Out + ((size_t)b * Qn + q0 + row) * Dn + h * 64);
#pragma unroll
    for (int i = 0; i < 16; i++) {
      float4 s4 = svp[i];
      op[i] = make_float4(s4.x * invK, s4.y * invK, s4.z * invK, s4.w * invK);
    }
    return;
  }

  __shared__ __align__(16) f16 Ks[2][64 * 128];
  __shared__ __align__(16) f16 Vs[2][128 * 64];

  const int wave = tid >> 6, lane = tid & 63;
  const int H = lane >> 5, l5 = lane & 31;
  const int qbase = q0 + wave * 32;
  const bool wact = qbase < vl;
  const int q_lane = qbase + l5;
  const float sc = (q_lane >= vl) ? 0.f : SCALE;

  const int krow = (l5 & 0x13) | ((l5 & 4) << 1) | ((l5 & 8) >> 1);
  const int krow7 = krow & 7;

  f16x8_t qf[8];
  if (wact) {
    const f16* qp = Qh + ((size_t)b * Qn + q_lane) * Dn + 8 * H;
#pragma unroll
    for (int s = 0; s < 8; s++) qf[s] = *(const f16x8_t*)(qp + 16 * s);
  }

  f32x16_t O[4];
#pragma unroll
  for (int i = 0; i < 4; i++) O[i] = (f32x16_t)(0.f);
  float l_lane = 0.f;

  const char* KgT = (const char*)Kh + ((size_t)b * Kn << 8);
  const char* VgT = (const char*)Vt + ((size_t)(b * (Kn / 64)) << 14);

  {
    const char* kg = KgT + wave * 4096 + lane * 16;
    const char* vg = VgT + wave * 4096 + lane * 16;
    f16* kl = Ks[0] + wave * 2048;
    f16* vli = Vs[0] + wave * 2048;
#pragma unroll
    for (int i = 0; i < 4; i++) {
      g2l16(kg + i * 1024, kl + i * 512);
      g2l16(vg + i * 1024, vli + i * 512);
    }
  }
  __syncthreads();

  int buf = 0;
  for (int sl = 0; sl < 32; sl++) {
    if (sl < 31) {
      const char* kg = KgT + (size_t)(sl + 1) * 16384 + wave * 4096 + lane * 16;
      const char* vg = VgT + (size_t)(sl + 1) * 16384 + wave * 4096 + lane * 16;
      f16* kl = Ks[buf ^ 1] + wave * 2048;
      f16* vli = Vs[buf ^ 1] + wave * 2048;
#pragma unroll
      for (int i = 0; i < 4; i++) {
        g2l16(kg + i * 1024, kl + i * 512);
        g2l16(vg + i * 1024, vli + i * 512);
      }
    }

    if (wact) {
#pragma unroll
      for (int sub = 0; sub < 2; sub++) {
        f32x16_t T = (f32x16_t)(0.f);
        const f16* krp = Ks[buf] + ((sub * 32 + krow) << 7);
#pragma unroll
        for (int s = 0; s < 8; s++) {
          const int G = 2 * s + H;
          const int gs = (G & 8) | ((G & 7) ^ krow7);
          f16x8_t kf = *(const f16x8_t*)(krp + (gs << 3));
          T = __builtin_amdgcn_mfma_f32_32x32x16_f16(kf, qf[s], T, 0, 0, 0);
        }
        f16x8_t pf0, pf1;
        float ls = 0.f;
#pragma unroll
        for (int r = 0; r < 8; r++) {
          float p = __expf(T[r] * sc);
          ls += p;
          pf0[r] = (f16)p;
        }
#pragma unroll
        for (int r = 8; r < 16; r++) {
          float p = __expf(T[r] * sc);
          ls += p;
          pf1[r - 8] = (f16)p;
        }
        l_lane += ls;
#pragma unroll
        for (int dt = 0; dt < 4; dt++) {
          const f16* vrp = Vs[buf] + ((dt * 32 + l5) << 6);
          const int G0 = sub * 4 + H, G1 = sub * 4 + 2 + H;
          const int gs0 = G0 ^ (l5 & 7);
          const int gs1 = G1 ^ (l5 & 7);
          f16x8_t vf0 = *(const f16x8_t*)(vrp + (gs0 << 3));
          f16x8_t vf1 = *(const f16x8_t*)(vrp + (gs1 << 3));
          O[dt] = __builtin_amdgcn_mfma_f32_32x32x16_f16(pf0, vf0, O[dt], 0, 0, 0);
          O[dt] = __builtin_amdgcn_mfma_f32_32x32x16_f16(pf1, vf1, O[dt], 0, 0, 0);
        }
      }
    }
    __syncthreads();
    buf ^= 1;
  }

  float* op = Out + ((size_t)b * Qn + qbase) * Dn;
  if (wact) {
    float ll = l_lane + __shfl_xor(l_lane, 32);
    float inv[16];
#pragma unroll
    for (int r = 0; r < 16; r++) {
      const int qrow = (r & 3) + 8 * (r >> 2) + 4 * H;
      inv[r] = 1.0f / __shfl(ll, qrow);
    }
#pragma unroll
    for (int dt = 0; dt < 4; dt++) {
#pragma unroll
      for (int r = 0; r < 16; r++) {
        const int qrow = (r & 3) + 8 * (r >> 2) + 4 * H;
        op[(size_t)qrow * Dn + dt * 32 + l5] = O[dt][r] * inv[r];
      }
    }
  } else {
    const float invK = 1.0f / (float)Kn;
#pragma unroll
    for (int dt = 0; dt < 4; dt++) {
      const float svv = sv[b * Dn + dt * 32 + l5] * invK;
#pragma unroll
      for (int r = 0; r < 16; r++) {
        const int qrow = (r & 3) + 8 * (r >> 2) + 4 * H;
        op[(size_t)qrow * Dn + dt * 32 + l5] = svv;
      }
    }
  }
}

// ---------------- combine: out = sum_s O_s / sum_s l_s; masked rows = mean(V)
// grid (32, 16) block 256; 64 q-rows per block, 8 d per thread.  [verbatim R0]

template <int S>
__global__ void __launch_bounds__(256) combine_kernel(
    const f16* __restrict__ Po, const float* __restrict__ Lb,
    const float* __restrict__ sv, const int* __restrict__ vlp,
    float* __restrict__ Out) {
  const int b = blockIdx.y, q0 = blockIdx.x * 64;
  const int vl = load_vl(vlp, b);
  const int tid = threadIdx.x;

  __shared__ float linv[64];
  if (tid < 64) {
    float s = 0.f;
#pragma unroll
    for (int sg = 0; sg < S; sg++) s += Lb[(size_t)(sg * Bn + b) * Qn + q0 + tid];
    linv[tid] = 1.0f / s;
  }
  __syncthreads();

  const int row16 = tid >> 4;     // 0..15
  const int d8 = (tid & 15) * 8;  // 0..120
  const float invK = 1.0f / (float)Kn;
  float mv[8];
#pragma unroll
  for (int j = 0; j < 8; j++) mv[j] = sv[b * Dn + d8 + j] * invK;

#pragma unroll
  for (int pass = 0; pass < 4; pass++) {
    const int row = pass * 16 + row16;
    const int q = q0 + row;
    float acc[8];
    if (q >= vl) {
#pragma unroll
      for (int j = 0; j < 8; j++) acc[j] = mv[j];
    } else {
#pragma unroll
      for (int j = 0; j < 8; j++) acc[j] = 0.f;
#pragma unroll
      for (int sg = 0; sg < S; sg++) {
        f16x8_t v = *(const f16x8_t*)(Po + ((size_t)(sg * Bn + b) * Qn + q) * Dn + d8);
#pragma unroll
        for (int j = 0; j < 8; j++) acc[j] += (float)v[j];
      }
      const float li = linv[row];
#pragma unroll
      for (int j = 0; j < 8; j++) acc[j] *= li;
    }
    float4 o0 = make_float4(acc[0], acc[1], acc[2], acc[3]);
    float4 o1 = make_float4(acc[4], acc[5], acc[6], acc[7]);
    float* op = Out + ((size_t)b * Qn + q) * Dn + d8;
    *(float4*)op = o0;
    *(float4*)(op + 4) = o1;
  }
}

// ---------------- launch ----------------

extern "C" void kernel_launch(void* const* d_in, const int* in_sizes, int n_in,
                              void* d_out, int out_size, void* d_ws, size_t ws_size,
                              hipStream_t stream) {
  const float* Qg = (const float*)d_in[0];
  const float* Kg = (const float*)d_in[1];
  const float* Vg = (const float*)d_in[2];
  const int* vl = (const int*)d_in[3];
  float* Out = (float*)d_out;

  char* ws = (char*)d_ws;
  const size_t kv = (size_t)Bn * Kn * Dn * 2;  // 8.39 MB each
  float* sumV = (float*)ws;                    // 8 KB
  f16* Kh = (f16*)(ws + 8192);
  f16* Vt = (f16*)(ws + 8192 + kv);
  f16* Qh = (f16*)(ws + 8192 + 2 * kv);

  const size_t plane = (size_t)Bn * Qn * Dn * 2;  // 8.39 MB
  const size_t lplane = (size_t)Bn * Qn * 4;      // 128 KB
  const size_t base = 8192 + 3 * kv;
  const size_t need4 = base + 4 * plane + 4 * lplane;  // ~59.3 MB
  const size_t need1 = base;                           // ~25.2 MB

  hipMemsetAsync(sumV, 0, Bn * Dn * sizeof(float), stream);

  prep_kernel<<<dim3(32, 4, Bn), dim3(32, 8), 0, stream>>>(
      Qg, Kg, Vg, Qh, Kh, Vt, sumV);

  if (ws_size >= need4) {
    // primary: SEG=4, ~2048 active waves, combine closes softmax
    f16* Po = (f16*)(ws + base);
    float* Lb = (float*)(ws + base + 4 * plane);
    // x=b fastest -> linear%8 = b%8 -> per-batch K/V XCD-local
    flash4<<<dim3(Bn, 16, 4), 256, 0, stream>>>(Qh, Kh, Vt, vl, Po, Lb);
    combine_kernel<4><<<dim3(Qn / 64, Bn), 256, 0, stream>>>(Po, Lb, sumV, vl, Out);
  } else {
    // fallback: R10 single-pass (proven passing)
    flash_sp<<<dim3(Bn, 16), 256, 0, stream>>>(Qh, Kh, Vt, vl, sumV, Out);
  }
}